// Round 20
// baseline (339.514 us; speedup 1.0000x reference)
//
#include <hip/hip_runtime.h>

typedef unsigned short u16;
typedef __attribute__((ext_vector_type(8))) _Float16 hfrag8;  // 8 f16 = 4 VGPRs (MFMA A/B frag)
typedef __attribute__((ext_vector_type(4))) float f32x4;      // MFMA C/D frag

__device__ __forceinline__ float bu2f(u16 u) { return __uint_as_float(((unsigned)u) << 16); }
__device__ __forceinline__ u16 f2bu(float f) {
    unsigned x = __float_as_uint(f);
    return (u16)((x + 0x7fffu + ((x >> 16) & 1u)) >> 16);   // RNE f32->bf16
}
__device__ __forceinline__ u16 f2hu(float f) {              // f32 -> f16 bit pattern (RNE)
    _Float16 h = (_Float16)f;
    return __builtin_bit_cast(u16, h);
}
__device__ __forceinline__ float ldf(const void* p, int i, bool f32) {
    return f32 ? ((const float*)p)[i] : bu2f(((const u16*)p)[i]);
}
// silu via v_rcp_f32 (1 ulp) instead of IEEE divide chain
__device__ __forceinline__ float siluf(float x) {
    return x * __builtin_amdgcn_rcpf(1.0f + __expf(-x));
}
// packed f32x2 -> f16x2 bits (v_cvt_pkrtz_f16_f32)
__device__ __forceinline__ unsigned pkh(float a, float b) {
    return __builtin_bit_cast(unsigned, __builtin_amdgcn_cvt_pkrtz(a, b));
}
// in-block dtype detection; works for any blockDim >= 256
__device__ __forceinline__ bool detect_f32(const void* nf, int t) {
    const u16* p = (const u16*)nf;
    int ext = 0;
    if (t < 256) {
        u16 v = p[t * 2];
        int e = (v >> 7) & 0xFF;
        ext = (e >= 140 || e == 0) ? 1 : 0;
    }
    return __syncthreads_count(ext) > 32;
}

// ---------------------------------------------------------------------------
// PREP (fused): blocks [0,256) = per-node precompute, [256,767) = T table,
// [767,895) = weight re-layout to fragment-major "X layout":
//   X[((n>>4)*8 + (k>>5))*512 + (n&15)*32 + (k&31)] = W[k][n]  (f16)
// ---------------------------------------------------------------------------
__global__ __launch_bounds__(256) void prep_kernel(
    const void* __restrict__ coords, const void* __restrict__ nf,
    const void* __restrict__ We1, const void* __restrict__ be1,
    const void* __restrict__ We2, const void* __restrict__ Wc1,
    float* __restrict__ cbar, float* __restrict__ pi2, float* __restrict__ qd,
    float* __restrict__ Ttab, u16* __restrict__ We2X, u16* __restrict__ Wc1X)
{
    const int t = threadIdx.x;
    const bool f32 = detect_f32(nf, t);
    const int blk = blockIdx.x;

    __shared__ float nf_l[4][128];
    __shared__ float ctmp[4][12];
    __shared__ float cb_l[4][3];
    __shared__ float pe[128];
    __shared__ u16 tile[32][33];

    if (blk < 256) {
        // ---- per-node precompute: cbar, pi2, qd ----
        const int row0 = blk * 4;
        for (int idx = t; idx < 512; idx += 256) {
            int r = idx >> 7, k = idx & 127;
            nf_l[r][k] = ldf(nf, (row0 + r) * 128 + k, f32);
        }
        if (t < 48) ctmp[t / 12][t % 12] = ldf(coords, row0 * 12 + t, f32);
        __syncthreads();
        if (t < 12) {
            int r = t / 3, x = t % 3;
            float m = 0.25f * (ctmp[r][x] + ctmp[r][3 + x] + ctmp[r][6 + x] + ctmp[r][9 + x]);
            cb_l[r][x] = m;
            cbar[(row0 + r) * 3 + x] = m;
        }
        __syncthreads();
        const int n = t;
        float accP[4] = {0.f, 0.f, 0.f, 0.f}, accQ[4] = {0.f, 0.f, 0.f, 0.f};
        for (int k = 0; k < 128; k++) {
            float w1 = ldf(We1, k * 256 + n, f32);
            float w2 = ldf(We1, (128 + k) * 256 + n, f32);
#pragma unroll
            for (int r = 0; r < 4; r++) {
                accP[r] += nf_l[r][k] * w1;
                accQ[r] += nf_l[r][k] * w2;
            }
        }
        float wx = ldf(We1, 384 * 256 + n, f32);
        float wy = ldf(We1, 385 * 256 + n, f32);
        float wz = ldf(We1, 386 * 256 + n, f32);
        float b1 = ldf(be1, n, f32);
#pragma unroll
        for (int r = 0; r < 4; r++) {
            float d = cb_l[r][0] * wx + cb_l[r][1] * wy + cb_l[r][2] * wz;
            pi2[(row0 + r) * 256 + n] = accP[r] + d + b1;
            qd[(row0 + r) * 256 + n]  = accQ[r] - d;
        }
    } else if (blk < 767) {
        // ---- T[d+255][n] = sinusoidal_pe(d) @ We1[256:384] ----
        const float d = (float)(blk - 511);           // d in [-255,255]
        if (t < 64) {
            float ang = d * 3.14159265358979323846f * exp2f(-(float)t * 0.125f);
            pe[t] = sinf(ang);
            pe[64 + t] = cosf(ang);
        }
        __syncthreads();
        float acc = 0.f;
        for (int k = 0; k < 128; k++) acc += pe[k] * ldf(We1, (256 + k) * 256 + t, f32);
        Ttab[(blk - 256) * 256 + t] = acc;
    } else {
        // ---- re-layout We2, Wc1 (256x256) -> fragment-major X layout ----
        int tbf = blk - 767;
        int mat = tbf >> 6;
        int tb = tbf & 63;
        int bx = tb & 7, by = tb >> 3;
        const void* src = mat ? Wc1 : We2;
        u16* dst = mat ? Wc1X : We2X;
        int tx = threadIdx.x & 31, ty = threadIdx.x >> 5;
#pragma unroll
        for (int p = 0; p < 4; p++) {
            int r = by * 32 + ty + p * 8;              // k index
            tile[ty + p * 8][tx] = f2hu(ldf(src, r * 256 + bx * 32 + tx, f32));
        }
        __syncthreads();
        // tile[a][b] = W[k=by*32+a][n=bx*32+b]
#pragma unroll
        for (int p = 0; p < 4; p++) {
            int n = bx * 32 + ty + p * 8;              // output row (col of W)
            dst[((n >> 4) * 8 + by) * 512 + (n & 15) * 32 + tx] = tile[tx][ty + p * 8];
        }
    }
}

// ---------------------------------------------------------------------------
// B: fused edge kernel: 512 threads = 8 waves x 32 cols, j in 4 CHUNKS OF
// 64 (was 2x128). r17/r19 plateau diagnosis: occupancy stuck at 1 block/CU
// (22%) despite LDS/VGPR appearing to permit 2 - the 73 KB U buffer is the
// suspect (allocation granularity / scheduler conservatism). U[64][280] =
// 35.8 KB makes 2-block residency unambiguous: LDS 2x37=74 << 160, VGPR
// acc[4][2]=32 -> demand ~95, 4 waves/SIMD x ~96 = 384 < 512. Target:
// 16 waves/CU = 4 waves/SIMD (r16->r17's 1->2 waves/SIMD gave -29%; same
// mechanism again). Cost: weight L2 re-stream x2 (~+15us spread), barriers
// 8->16. X-layout weights, swapped MFMAs, bias-init accs (r19 lineage).
// ---------------------------------------------------------------------------
__global__ __launch_bounds__(512, 1)
void edge_kernel(
    const int* __restrict__ resid,
    const float* __restrict__ pi2, const float* __restrict__ qd,
    const float* __restrict__ Ttab, const float* __restrict__ cbar,
    const u16* __restrict__ We2X, const u16* __restrict__ Wc1X,
    const void* __restrict__ be2, const void* __restrict__ bc1,
    const void* __restrict__ Wc2, const void* __restrict__ bc2,
    const void* __restrict__ nf,
    float* __restrict__ agg_out, float* __restrict__ cupd_out)
{
    const int t = threadIdx.x;
    const bool f32 = detect_f32(nf, t);
    const int node = blockIdx.x;          // b*256 + i
    const int b = node >> 8;
    const int lane = t & 63, w = t >> 6;  // 8 waves; wave w owns cols [32w,32w+32)
    const int c = lane & 15, q = lane >> 4;

    __shared__ __align__(16) u16 U[64][280];   // h1 / msg alias, f16 bits (35.8 KB)
    __shared__ int relidx[256];
    __shared__ float fin[8][4];

    if (t < 256) relidx[t] = resid[node] - resid[(b << 8) + t] + 255;
    const float bc2q = 0.125f * ldf(bc2, 0, f32);  // bc2 folded per-wave (x8 waves)

    // per-lane column constants: component r of [nn] is col w*32+nn*16+q*4+r
    f32x4 be2i[2], bc1i[2];       // bias init values for the accumulators
    float4 wc2v[2];
#pragma unroll
    for (int nn = 0; nn < 2; nn++) {
        const int base = w * 32 + nn * 16 + q * 4;
        be2i[nn][0] = ldf(be2, base, f32);
        be2i[nn][1] = ldf(be2, base + 1, f32);
        be2i[nn][2] = ldf(be2, base + 2, f32);
        be2i[nn][3] = ldf(be2, base + 3, f32);
        bc1i[nn][0] = ldf(bc1, base, f32);
        bc1i[nn][1] = ldf(bc1, base + 1, f32);
        bc1i[nn][2] = ldf(bc1, base + 2, f32);
        bc1i[nn][3] = ldf(bc1, base + 3, f32);
        wc2v[nn] = make_float4(ldf(Wc2, base, f32), ldf(Wc2, base + 1, f32),
                               ldf(Wc2, base + 2, f32), ldf(Wc2, base + 3, f32));
    }

    // phase-1 mapping: wave w owns j rows [8w,8w+8); lane owns 4 k's
    const int kp = lane << 2;
    const float4 pv = *(const float4*)(pi2 + node * 256 + kp);  // pi2 slice in regs

    float aggv[2][4] = {{0.f}};                    // agg partials, all lanes
    float s0 = 0.f, s1 = 0.f, s2 = 0.f, s3 = 0.f;  // coord partials (q==0 lanes)

    __syncthreads();   // relidx visible

    for (int jc = 0; jc < 4; jc++) {
        const int j0 = jc << 6;
        // ---- P1: U = h1 = silu(pi2[i] + qd[j] + T[rel]), f16 into LDS ----
        {
            const float* qbase = qd + ((b << 8) + j0) * 256 + kp;
            const int r0 = w * 8;
#pragma unroll 4
            for (int jj = 0; jj < 8; jj++) {
                const int j = r0 + jj;
                const float4 qv = *(const float4*)(qbase + j * 256);
                const float4 tv = *(const float4*)(Ttab + relidx[j0 + j] * 256 + kp);
                uint2 pk;
                pk.x = pkh(siluf(pv.x + qv.x + tv.x), siluf(pv.y + qv.y + tv.y));
                pk.y = pkh(siluf(pv.z + qv.z + tv.z), siluf(pv.w + qv.w + tv.w));
                *(uint2*)&U[j][kp] = pk;
            }
        }
        __syncthreads();   // S1: h1 complete

        // ---- P2 k-loop (swapped): acc[m][nn] = (We2^T . h1^T) + be2 ----
        // acc initialized with bias: reg r of acc[m][nn] covers col
        // w*32+nn*16+q*4+r; bias col-indexed, j-independent -> exact.
        f32x4 acc[4][2];
#pragma unroll
        for (int m = 0; m < 4; m++) {
            acc[m][0] = be2i[0];
            acc[m][1] = be2i[1];
        }
#pragma unroll 2
        for (int ks = 0; ks < 8; ks++) {
            const int kb = ks * 32 + q * 8;
            hfrag8 wf[2];
#pragma unroll
            for (int nn = 0; nn < 2; nn++)
                wf[nn] = *(const hfrag8*)(We2X + ((w * 2 + nn) * 8 + ks) * 512 + c * 32 + q * 8);
            hfrag8 hm[4];
#pragma unroll
            for (int m = 0; m < 4; m++)
                hm[m] = *(const hfrag8*)&U[m * 16 + c][kb];
#pragma unroll
            for (int m = 0; m < 4; m++)
#pragma unroll
                for (int nn = 0; nn < 2; nn++)
                    acc[m][nn] = __builtin_amdgcn_mfma_f32_16x16x32_f16(wf[nn], hm[m], acc[m][nn], 0, 0, 0);
        }
        __syncthreads();   // S2: all h1 reads done; U may be overwritten

        // ---- P2 epilogue: silu -> U = msg (b64 packed); agg in registers ----
#pragma unroll
        for (int m = 0; m < 4; m++) {
            u16* mrow = &U[m * 16 + c][w * 32 + q * 4];
#pragma unroll
            for (int nn = 0; nn < 2; nn++) {
                float sa = siluf(acc[m][nn][0]);
                float sb = siluf(acc[m][nn][1]);
                float sc_ = siluf(acc[m][nn][2]);
                float sd = siluf(acc[m][nn][3]);
                aggv[nn][0] += sa; aggv[nn][1] += sb;
                aggv[nn][2] += sc_; aggv[nn][3] += sd;
                uint2 pk;
                pk.x = pkh(sa, sb);
                pk.y = pkh(sc_, sd);
                *(uint2*)(mrow + nn * 16) = pk;
            }
        }
        __syncthreads();   // S3: msg complete

        // ---- P3 k-loop (swapped): acc[m][nn] = (Wc1^T . msg^T) + bc1 ----
#pragma unroll
        for (int m = 0; m < 4; m++) {
            acc[m][0] = bc1i[0];
            acc[m][1] = bc1i[1];
        }
#pragma unroll 2
        for (int ks = 0; ks < 8; ks++) {
            const int kb = ks * 32 + q * 8;
            hfrag8 wf[2];
#pragma unroll
            for (int nn = 0; nn < 2; nn++)
                wf[nn] = *(const hfrag8*)(Wc1X + ((w * 2 + nn) * 8 + ks) * 512 + c * 32 + q * 8);
            hfrag8 mm[4];
#pragma unroll
            for (int m = 0; m < 4; m++)
                mm[m] = *(const hfrag8*)&U[m * 16 + c][kb];
#pragma unroll
            for (int m = 0; m < 4; m++)
#pragma unroll
                for (int nn = 0; nn < 2; nn++)
                    acc[m][nn] = __builtin_amdgcn_mfma_f32_16x16x32_f16(wf[nn], mm[m], acc[m][nn], 0, 0, 0);
        }
        __syncthreads();   // S4: all msg reads done; next P1 may overwrite U

        // ---- P3 epilogue: row-local dot; 2 shuffles per m; coord partials ----
#pragma unroll
        for (int m = 0; m < 4; m++) {
            float dv = 0.f;
#pragma unroll
            for (int nn = 0; nn < 2; nn++) {
                dv += siluf(acc[m][nn][0]) * wc2v[nn].x;
                dv += siluf(acc[m][nn][1]) * wc2v[nn].y;
                dv += siluf(acc[m][nn][2]) * wc2v[nn].z;
                dv += siluf(acc[m][nn][3]) * wc2v[nn].w;
            }
            dv += __shfl_xor(dv, 16);    // sum the 4 q-slices of the wave's 32 cols
            dv += __shfl_xor(dv, 32);
            if (q == 0) {                // lane c holds wave-partial cu for j=j0+m*16+c
                const float vb = dv + bc2q;
                const float* cp = cbar + ((b << 8) + j0 + m * 16 + c) * 3;
                s0 += vb;
                s1 += vb * cp[0];
                s2 += vb * cp[1];
                s3 += vb * cp[2];
            }
        }
    }

    // ---- agg final: reduce over c-lanes once, store float4 per nn ----
#pragma unroll
    for (int nn = 0; nn < 2; nn++)
#pragma unroll
        for (int r = 0; r < 4; r++) {
            float v = aggv[nn][r];
            v += __shfl_xor(v, 1);
            v += __shfl_xor(v, 2);
            v += __shfl_xor(v, 4);
            v += __shfl_xor(v, 8);
            aggv[nn][r] = v;
        }
    if (c == 0) {
#pragma unroll
        for (int nn = 0; nn < 2; nn++) {
            float4 o = make_float4(aggv[nn][0], aggv[nn][1], aggv[nn][2], aggv[nn][3]);
            *(float4*)(agg_out + node * 256 + w * 32 + nn * 16 + q * 4) = o;
        }
    }

    // ---- coord partials live on q==0 lanes (c=0..15): reduce over c ----
#pragma unroll
    for (int d = 1; d < 16; d <<= 1) {
        s0 += __shfl_xor(s0, d);
        s1 += __shfl_xor(s1, d);
        s2 += __shfl_xor(s2, d);
        s3 += __shfl_xor(s3, d);
    }
    if (lane == 0) { fin[w][0] = s0; fin[w][1] = s1; fin[w][2] = s2; fin[w][3] = s3; }
    __syncthreads();
    if (t == 0) {
        float S0 = 0.f, S1 = 0.f, S2 = 0.f, S3 = 0.f;
#pragma unroll
        for (int u = 0; u < 8; u++) {
            S0 += fin[u][0]; S1 += fin[u][1]; S2 += fin[u][2]; S3 += fin[u][3];
        }
        // coord_upd = (sum cu)*cbar_i - sum(cu*cbar_j)
        const float cx = cbar[node * 3 + 0], cy = cbar[node * 3 + 1], cz = cbar[node * 3 + 2];
        cupd_out[node * 3 + 0] = S0 * cx - S1;
        cupd_out[node * 3 + 1] = S0 * cy - S2;
        cupd_out[node * 3 + 2] = S0 * cz - S3;
    }
}

// ---------------------------------------------------------------------------
// OUT (fused): blocks [0,128) = node MLP + LayerNorm -> d_out[12288..],
// blocks [128,176) = updated coords -> d_out[0..12288).
// ---------------------------------------------------------------------------
__global__ __launch_bounds__(256) void out_kernel(
    const void* __restrict__ nf, const float* __restrict__ agg,
    const void* __restrict__ Wn1, const void* __restrict__ bn1,
    const void* __restrict__ Wn2, const void* __restrict__ bn2,
    const void* __restrict__ gamma, const void* __restrict__ beta,
    const void* __restrict__ coords, const void* __restrict__ mask,
    const float* __restrict__ cupd, void* __restrict__ d_out)
{
    const int t = threadIdx.x;
    const bool f32 = detect_f32(nf, t);

    if (blockIdx.x >= 128) {
        // ---- coords part ----
        int idx = (blockIdx.x - 128) * 256 + t;
        if (idx < 4 * 256 * 4 * 3) {
            int x = idx % 3;
            int a = (idx / 3) & 3;
            int node = idx / 12;
            float v = ldf(coords, idx, f32) + cupd[node * 3 + x] * ldf(mask, node * 4 + a, f32);
            if (f32) ((float*)d_out)[idx] = v;
            else     ((u16*)d_out)[idx] = f2bu(v);
        }
        return;
    }

    // ---- node MLP + LN ----
    const int row0 = blockIdx.x * 8;
    __shared__ float x_l[8][384];
    __shared__ float hs[8][256];
    __shared__ float ho[8][128];
    for (int idx = t; idx < 8 * 384; idx += 256) {
        int r = idx / 384, k = idx % 384;
        x_l[r][k] = (k < 128) ? ldf(nf, (row0 + r) * 128 + k, f32)
                              : agg[(row0 + r) * 256 + (k - 128)];
    }
    __syncthreads();
    {
        float a1[8] = {0.f, 0.f, 0.f, 0.f, 0.f, 0.f, 0.f, 0.f};
        for (int k = 0; k < 384; k++) {
            float wv = ldf(Wn1, k * 256 + t, f32);
#pragma unroll
            for (int r = 0; r < 8; r++) a1[r] += x_l[r][k] * wv;
        }
        float b1 = ldf(bn1, t, f32);
#pragma unroll
        for (int r = 0; r < 8; r++) hs[r][t] = siluf(a1[r] + b1);
    }
    __syncthreads();
    {
        int cc = t & 127, rg = (t >> 7) * 4;
        float a2[4] = {0.f, 0.f, 0.f, 0.f};
        for (int k = 0; k < 256; k++) {
            float wv = ldf(Wn2, k * 128 + cc, f32);
#pragma unroll
            for (int r = 0; r < 4; r++) a2[r] += hs[rg + r][k] * wv;
        }
        float b2 = ldf(bn2, cc, f32);
#pragma unroll
        for (int r = 0; r < 4; r++) ho[rg + r][cc] = a2[r] + b2;
    }
    __syncthreads();
    {
        int row = t >> 5, s = t & 31;
        float sm = 0.f, sq = 0.f;
#pragma unroll
        for (int u = 0; u < 4; u++) {
            float v = ho[row][s + 32 * u];
            sm += v; sq += v * v;
        }
#pragma unroll
        for (int d = 1; d < 32; d <<= 1) {
            sm += __shfl_xor(sm, d);
            sq += __shfl_xor(sq, d);
        }
        float mu = sm * (1.f / 128.f);
        float var = sq * (1.f / 128.f) - mu * mu;
        float inv = rsqrtf(var + 1e-5f);
#pragma unroll
        for (int u = 0; u < 4; u++) {
            int cc = s + 32 * u;
            float y = (ho[row][cc] - mu) * inv;
            float outv = y * ldf(gamma, cc, f32) + ldf(beta, cc, f32);
            int oi = 12288 + (row0 + row) * 128 + cc;
            if (f32) ((float*)d_out)[oi] = outv;
            else     ((u16*)d_out)[oi] = f2bu(outv);
        }
    }
}

extern "C" void kernel_launch(void* const* d_in, const int* in_sizes, int n_in,
                              void* d_out, int out_size, void* d_ws, size_t ws_size,
                              hipStream_t stream)
{
    const void* coords = d_in[0];
    const void* nf     = d_in[1];
    const void* mask   = d_in[2];
    const int* resid   = (const int*)d_in[3];
    const void* We1 = d_in[4];
    const void* be1 = d_in[5];
    const void* We2 = d_in[6];
    const void* be2 = d_in[7];
    const void* Wn1 = d_in[8];
    const void* bn1 = d_in[9];
    const void* Wn2 = d_in[10];
    const void* bn2 = d_in[11];
    const void* gamma = d_in[12];
    const void* beta  = d_in[13];
    const void* Wc1 = d_in[14];
    const void* bc1 = d_in[15];
    const void* Wc2 = d_in[16];
    const void* bc2 = d_in[17];

    // workspace layout: [pad][f32 arrays][f16 weight arrays] ~3.96 MB
    float* f   = (float*)d_ws + 16;
    float* cbar = f;                 // 1024*3
    float* pi2  = cbar + 3072;       // 1024*256
    float* qd   = pi2 + 262144;      // 1024*256
    float* Ttab = qd + 262144;       // 511*256
    float* agg  = Ttab + 130816;     // 1024*256
    float* cupd = agg + 262144;      // 1024*3
    u16* We2X = (u16*)(cupd + 3072); // 256*256 f16, fragment-major X layout
    u16* Wc1X = We2X + 65536;        // 256*256 f16

    hipLaunchKernelGGL(prep_kernel, dim3(895), dim3(256), 0, stream,
                       coords, nf, We1, be1, We2, Wc1, cbar, pi2, qd, Ttab, We2X, Wc1X);
    hipLaunchKernelGGL(edge_kernel, dim3(1024), dim3(512), 0, stream,
                       resid, pi2, qd, Ttab, cbar, We2X, Wc1X, be2, bc1, Wc2, bc2, nf, agg, cupd);
    hipLaunchKernelGGL(out_kernel, dim3(176), dim3(256), 0, stream,
                       nf, agg, Wn1, bn1, Wn2, bn2, gamma, beta, coords, mask, cupd, d_out);
}

// Round 21
// 315.186 us; speedup vs baseline: 1.0772x; 1.0772x over previous
//
#include <hip/hip_runtime.h>

typedef unsigned short u16;
typedef __attribute__((ext_vector_type(8))) _Float16 hfrag8;  // 8 f16 = 4 VGPRs (MFMA A/B frag)
typedef __attribute__((ext_vector_type(4))) float f32x4;      // MFMA C/D frag

__device__ __forceinline__ float bu2f(u16 u) { return __uint_as_float(((unsigned)u) << 16); }
__device__ __forceinline__ u16 f2bu(float f) {
    unsigned x = __float_as_uint(f);
    return (u16)((x + 0x7fffu + ((x >> 16) & 1u)) >> 16);   // RNE f32->bf16
}
__device__ __forceinline__ u16 f2hu(float f) {              // f32 -> f16 bit pattern (RNE)
    _Float16 h = (_Float16)f;
    return __builtin_bit_cast(u16, h);
}
__device__ __forceinline__ float ldf(const void* p, int i, bool f32) {
    return f32 ? ((const float*)p)[i] : bu2f(((const u16*)p)[i]);
}
// silu via v_rcp_f32 (1 ulp) instead of IEEE divide chain
__device__ __forceinline__ float siluf(float x) {
    return x * __builtin_amdgcn_rcpf(1.0f + __expf(-x));
}
// packed f32x2 -> f16x2 bits (v_cvt_pkrtz_f16_f32)
__device__ __forceinline__ unsigned pkh(float a, float b) {
    return __builtin_bit_cast(unsigned, __builtin_amdgcn_cvt_pkrtz(a, b));
}
// in-block dtype detection; works for any blockDim >= 256
__device__ __forceinline__ bool detect_f32(const void* nf, int t) {
    const u16* p = (const u16*)nf;
    int ext = 0;
    if (t < 256) {
        u16 v = p[t * 2];
        int e = (v >> 7) & 0xFF;
        ext = (e >= 140 || e == 0) ? 1 : 0;
    }
    return __syncthreads_count(ext) > 32;
}

// ---------------------------------------------------------------------------
// PREP (fused): blocks [0,256) = per-node precompute, [256,767) = T table,
// [767,895) = weight re-layout to fragment-major "X layout":
//   X[((n>>4)*8 + (k>>5))*512 + (n&15)*32 + (k&31)] = W[k][n]  (f16)
// ---------------------------------------------------------------------------
__global__ __launch_bounds__(256) void prep_kernel(
    const void* __restrict__ coords, const void* __restrict__ nf,
    const void* __restrict__ We1, const void* __restrict__ be1,
    const void* __restrict__ We2, const void* __restrict__ Wc1,
    float* __restrict__ cbar, float* __restrict__ pi2, float* __restrict__ qd,
    float* __restrict__ Ttab, u16* __restrict__ We2X, u16* __restrict__ Wc1X)
{
    const int t = threadIdx.x;
    const bool f32 = detect_f32(nf, t);
    const int blk = blockIdx.x;

    __shared__ float nf_l[4][128];
    __shared__ float ctmp[4][12];
    __shared__ float cb_l[4][3];
    __shared__ float pe[128];
    __shared__ u16 tile[32][33];

    if (blk < 256) {
        // ---- per-node precompute: cbar, pi2, qd ----
        const int row0 = blk * 4;
        for (int idx = t; idx < 512; idx += 256) {
            int r = idx >> 7, k = idx & 127;
            nf_l[r][k] = ldf(nf, (row0 + r) * 128 + k, f32);
        }
        if (t < 48) ctmp[t / 12][t % 12] = ldf(coords, row0 * 12 + t, f32);
        __syncthreads();
        if (t < 12) {
            int r = t / 3, x = t % 3;
            float m = 0.25f * (ctmp[r][x] + ctmp[r][3 + x] + ctmp[r][6 + x] + ctmp[r][9 + x]);
            cb_l[r][x] = m;
            cbar[(row0 + r) * 3 + x] = m;
        }
        __syncthreads();
        const int n = t;
        float accP[4] = {0.f, 0.f, 0.f, 0.f}, accQ[4] = {0.f, 0.f, 0.f, 0.f};
        for (int k = 0; k < 128; k++) {
            float w1 = ldf(We1, k * 256 + n, f32);
            float w2 = ldf(We1, (128 + k) * 256 + n, f32);
#pragma unroll
            for (int r = 0; r < 4; r++) {
                accP[r] += nf_l[r][k] * w1;
                accQ[r] += nf_l[r][k] * w2;
            }
        }
        float wx = ldf(We1, 384 * 256 + n, f32);
        float wy = ldf(We1, 385 * 256 + n, f32);
        float wz = ldf(We1, 386 * 256 + n, f32);
        float b1 = ldf(be1, n, f32);
#pragma unroll
        for (int r = 0; r < 4; r++) {
            float d = cb_l[r][0] * wx + cb_l[r][1] * wy + cb_l[r][2] * wz;
            pi2[(row0 + r) * 256 + n] = accP[r] + d + b1;
            qd[(row0 + r) * 256 + n]  = accQ[r] - d;
        }
    } else if (blk < 767) {
        // ---- T[d+255][n] = sinusoidal_pe(d) @ We1[256:384] ----
        const float d = (float)(blk - 511);           // d in [-255,255]
        if (t < 64) {
            float ang = d * 3.14159265358979323846f * exp2f(-(float)t * 0.125f);
            pe[t] = sinf(ang);
            pe[64 + t] = cosf(ang);
        }
        __syncthreads();
        float acc = 0.f;
        for (int k = 0; k < 128; k++) acc += pe[k] * ldf(We1, (256 + k) * 256 + t, f32);
        Ttab[(blk - 256) * 256 + t] = acc;
    } else {
        // ---- re-layout We2, Wc1 (256x256) -> fragment-major X layout ----
        int tbf = blk - 767;
        int mat = tbf >> 6;
        int tb = tbf & 63;
        int bx = tb & 7, by = tb >> 3;
        const void* src = mat ? Wc1 : We2;
        u16* dst = mat ? Wc1X : We2X;
        int tx = threadIdx.x & 31, ty = threadIdx.x >> 5;
#pragma unroll
        for (int p = 0; p < 4; p++) {
            int r = by * 32 + ty + p * 8;              // k index
            tile[ty + p * 8][tx] = f2hu(ldf(src, r * 256 + bx * 32 + tx, f32));
        }
        __syncthreads();
        // tile[a][b] = W[k=by*32+a][n=bx*32+b]
#pragma unroll
        for (int p = 0; p < 4; p++) {
            int n = bx * 32 + ty + p * 8;              // output row (col of W)
            dst[((n >> 4) * 8 + by) * 512 + (n & 15) * 32 + tx] = tile[tx][ty + p * 8];
        }
    }
}

// ---------------------------------------------------------------------------
// B: fused edge kernel: 512 threads = 8 waves x 32 cols, j in 2 chunks of
// 128 (FINAL config, r17/r19 best measured: edge 144.5us, total ~318us).
// Session findings baked in:
//  - chunk=128 + fragment-major X-layout weights (r13: 306->200, kills the
//    per-chunk weight re-stream that bound r0-r12 at ~290-330us)
//  - 8 waves x 32 cols -> 2 waves/SIMD co-resident (r17: 203->144.5)
//  - operand-swapped MFMAs (A=weights, B=h/msg): epilogues get 4
//    consecutive cols per reg quad -> b64 packed LDS writes, row-local
//    P3 dot (2 shuffles), reg-resident agg (r12)
//  - accumulators initialized with bias (r19, exact: acc reg r <-> col)
//  - single aliased U buffer, 4 barriers/chunk (race-free; r13 lineage)
// Dead ends measured: occupancy >22% unreachable (r15/r19/r20 all pin at
// 1 block/CU regardless of LDS/VGPR); 2x4 wave tiling (r18 -10%); forced
// waves_per_eu pins (r1/r6/r14: spill catastrophes); full unroll (r9).
// ---------------------------------------------------------------------------
__global__ __launch_bounds__(512, 1)
void edge_kernel(
    const int* __restrict__ resid,
    const float* __restrict__ pi2, const float* __restrict__ qd,
    const float* __restrict__ Ttab, const float* __restrict__ cbar,
    const u16* __restrict__ We2X, const u16* __restrict__ Wc1X,
    const void* __restrict__ be2, const void* __restrict__ bc1,
    const void* __restrict__ Wc2, const void* __restrict__ bc2,
    const void* __restrict__ nf,
    float* __restrict__ agg_out, float* __restrict__ cupd_out)
{
    const int t = threadIdx.x;
    const bool f32 = detect_f32(nf, t);
    const int node = blockIdx.x;          // b*256 + i
    const int b = node >> 8;
    const int lane = t & 63, w = t >> 6;  // 8 waves; wave w owns cols [32w,32w+32)
    const int c = lane & 15, q = lane >> 4;

    __shared__ __align__(16) u16 U[128][280];   // h1 / msg alias, f16 bits
    __shared__ int relidx[256];
    __shared__ float fin[8][4];

    if (t < 256) relidx[t] = resid[node] - resid[(b << 8) + t] + 255;
    const float bc2q = 0.125f * ldf(bc2, 0, f32);  // bc2 folded per-wave (x8 waves)

    // per-lane column constants: component r of [nn] is col w*32+nn*16+q*4+r
    f32x4 be2i[2], bc1i[2];       // bias init values for the accumulators
    float4 wc2v[2];
#pragma unroll
    for (int nn = 0; nn < 2; nn++) {
        const int base = w * 32 + nn * 16 + q * 4;
        be2i[nn][0] = ldf(be2, base, f32);
        be2i[nn][1] = ldf(be2, base + 1, f32);
        be2i[nn][2] = ldf(be2, base + 2, f32);
        be2i[nn][3] = ldf(be2, base + 3, f32);
        bc1i[nn][0] = ldf(bc1, base, f32);
        bc1i[nn][1] = ldf(bc1, base + 1, f32);
        bc1i[nn][2] = ldf(bc1, base + 2, f32);
        bc1i[nn][3] = ldf(bc1, base + 3, f32);
        wc2v[nn] = make_float4(ldf(Wc2, base, f32), ldf(Wc2, base + 1, f32),
                               ldf(Wc2, base + 2, f32), ldf(Wc2, base + 3, f32));
    }

    // phase-1 mapping: wave w owns j rows [16w,16w+16); lane owns 4 k's
    const int kp = lane << 2;
    const float4 pv = *(const float4*)(pi2 + node * 256 + kp);  // pi2 slice in regs

    float aggv[2][4] = {{0.f}};                    // agg partials, all lanes
    float s0 = 0.f, s1 = 0.f, s2 = 0.f, s3 = 0.f;  // coord partials (q==0 lanes)

    __syncthreads();   // relidx visible

    for (int jc = 0; jc < 2; jc++) {
        const int j0 = jc << 7;
        // ---- P1: U = h1 = silu(pi2[i] + qd[j] + T[rel]), f16 into LDS ----
        {
            const float* qbase = qd + ((b << 8) + j0) * 256 + kp;
            const int r0 = w * 16;
#pragma unroll 4
            for (int jj = 0; jj < 16; jj++) {
                const int j = r0 + jj;
                const float4 qv = *(const float4*)(qbase + j * 256);
                const float4 tv = *(const float4*)(Ttab + relidx[j0 + j] * 256 + kp);
                uint2 pk;
                pk.x = pkh(siluf(pv.x + qv.x + tv.x), siluf(pv.y + qv.y + tv.y));
                pk.y = pkh(siluf(pv.z + qv.z + tv.z), siluf(pv.w + qv.w + tv.w));
                *(uint2*)&U[j][kp] = pk;
            }
        }
        __syncthreads();   // S1: h1 complete

        // ---- P2 k-loop (swapped): acc[m][nn] = (We2^T . h1^T) + be2 ----
        // acc initialized with bias: reg r of acc[m][nn] covers col
        // w*32+nn*16+q*4+r; bias col-indexed, j-independent -> exact.
        f32x4 acc[8][2];
#pragma unroll
        for (int m = 0; m < 8; m++) {
            acc[m][0] = be2i[0];
            acc[m][1] = be2i[1];
        }
#pragma unroll 2
        for (int ks = 0; ks < 8; ks++) {
            const int kb = ks * 32 + q * 8;
            hfrag8 wf[2];
#pragma unroll
            for (int nn = 0; nn < 2; nn++)
                wf[nn] = *(const hfrag8*)(We2X + ((w * 2 + nn) * 8 + ks) * 512 + c * 32 + q * 8);
            hfrag8 hm[8];
#pragma unroll
            for (int m = 0; m < 8; m++)
                hm[m] = *(const hfrag8*)&U[m * 16 + c][kb];
#pragma unroll
            for (int m = 0; m < 8; m++)
#pragma unroll
                for (int nn = 0; nn < 2; nn++)
                    acc[m][nn] = __builtin_amdgcn_mfma_f32_16x16x32_f16(wf[nn], hm[m], acc[m][nn], 0, 0, 0);
        }
        __syncthreads();   // S2: all h1 reads done; U may be overwritten

        // ---- P2 epilogue: silu -> U = msg (b64 packed); agg in registers ----
#pragma unroll
        for (int m = 0; m < 8; m++) {
            u16* mrow = &U[m * 16 + c][w * 32 + q * 4];
#pragma unroll
            for (int nn = 0; nn < 2; nn++) {
                float sa = siluf(acc[m][nn][0]);
                float sb = siluf(acc[m][nn][1]);
                float sc_ = siluf(acc[m][nn][2]);
                float sd = siluf(acc[m][nn][3]);
                aggv[nn][0] += sa; aggv[nn][1] += sb;
                aggv[nn][2] += sc_; aggv[nn][3] += sd;
                uint2 pk;
                pk.x = pkh(sa, sb);
                pk.y = pkh(sc_, sd);
                *(uint2*)(mrow + nn * 16) = pk;
            }
        }
        __syncthreads();   // S3: msg complete

        // ---- P3 k-loop (swapped): acc[m][nn] = (Wc1^T . msg^T) + bc1 ----
#pragma unroll
        for (int m = 0; m < 8; m++) {
            acc[m][0] = bc1i[0];
            acc[m][1] = bc1i[1];
        }
#pragma unroll 2
        for (int ks = 0; ks < 8; ks++) {
            const int kb = ks * 32 + q * 8;
            hfrag8 wf[2];
#pragma unroll
            for (int nn = 0; nn < 2; nn++)
                wf[nn] = *(const hfrag8*)(Wc1X + ((w * 2 + nn) * 8 + ks) * 512 + c * 32 + q * 8);
            hfrag8 mm[8];
#pragma unroll
            for (int m = 0; m < 8; m++)
                mm[m] = *(const hfrag8*)&U[m * 16 + c][kb];
#pragma unroll
            for (int m = 0; m < 8; m++)
#pragma unroll
                for (int nn = 0; nn < 2; nn++)
                    acc[m][nn] = __builtin_amdgcn_mfma_f32_16x16x32_f16(wf[nn], mm[m], acc[m][nn], 0, 0, 0);
        }
        __syncthreads();   // S4: all msg reads done; next P1 may overwrite U

        // ---- P3 epilogue: row-local dot; 2 shuffles per m; coord partials ----
#pragma unroll
        for (int m = 0; m < 8; m++) {
            float dv = 0.f;
#pragma unroll
            for (int nn = 0; nn < 2; nn++) {
                dv += siluf(acc[m][nn][0]) * wc2v[nn].x;
                dv += siluf(acc[m][nn][1]) * wc2v[nn].y;
                dv += siluf(acc[m][nn][2]) * wc2v[nn].z;
                dv += siluf(acc[m][nn][3]) * wc2v[nn].w;
            }
            dv += __shfl_xor(dv, 16);    // sum the 4 q-slices of the wave's 32 cols
            dv += __shfl_xor(dv, 32);
            if (q == 0) {                // lane c holds wave-partial cu for j=j0+m*16+c
                const float vb = dv + bc2q;
                const float* cp = cbar + ((b << 8) + j0 + m * 16 + c) * 3;
                s0 += vb;
                s1 += vb * cp[0];
                s2 += vb * cp[1];
                s3 += vb * cp[2];
            }
        }
    }

    // ---- agg final: reduce over c-lanes once, store float4 per nn ----
#pragma unroll
    for (int nn = 0; nn < 2; nn++)
#pragma unroll
        for (int r = 0; r < 4; r++) {
            float v = aggv[nn][r];
            v += __shfl_xor(v, 1);
            v += __shfl_xor(v, 2);
            v += __shfl_xor(v, 4);
            v += __shfl_xor(v, 8);
            aggv[nn][r] = v;
        }
    if (c == 0) {
#pragma unroll
        for (int nn = 0; nn < 2; nn++) {
            float4 o = make_float4(aggv[nn][0], aggv[nn][1], aggv[nn][2], aggv[nn][3]);
            *(float4*)(agg_out + node * 256 + w * 32 + nn * 16 + q * 4) = o;
        }
    }

    // ---- coord partials live on q==0 lanes (c=0..15): reduce over c ----
#pragma unroll
    for (int d = 1; d < 16; d <<= 1) {
        s0 += __shfl_xor(s0, d);
        s1 += __shfl_xor(s1, d);
        s2 += __shfl_xor(s2, d);
        s3 += __shfl_xor(s3, d);
    }
    if (lane == 0) { fin[w][0] = s0; fin[w][1] = s1; fin[w][2] = s2; fin[w][3] = s3; }
    __syncthreads();
    if (t == 0) {
        float S0 = 0.f, S1 = 0.f, S2 = 0.f, S3 = 0.f;
#pragma unroll
        for (int u = 0; u < 8; u++) {
            S0 += fin[u][0]; S1 += fin[u][1]; S2 += fin[u][2]; S3 += fin[u][3];
        }
        // coord_upd = (sum cu)*cbar_i - sum(cu*cbar_j)
        const float cx = cbar[node * 3 + 0], cy = cbar[node * 3 + 1], cz = cbar[node * 3 + 2];
        cupd_out[node * 3 + 0] = S0 * cx - S1;
        cupd_out[node * 3 + 1] = S0 * cy - S2;
        cupd_out[node * 3 + 2] = S0 * cz - S3;
    }
}

// ---------------------------------------------------------------------------
// OUT (fused): blocks [0,128) = node MLP + LayerNorm -> d_out[12288..],
// blocks [128,176) = updated coords -> d_out[0..12288).
// ---------------------------------------------------------------------------
__global__ __launch_bounds__(256) void out_kernel(
    const void* __restrict__ nf, const float* __restrict__ agg,
    const void* __restrict__ Wn1, const void* __restrict__ bn1,
    const void* __restrict__ Wn2, const void* __restrict__ bn2,
    const void* __restrict__ gamma, const void* __restrict__ beta,
    const void* __restrict__ coords, const void* __restrict__ mask,
    const float* __restrict__ cupd, void* __restrict__ d_out)
{
    const int t = threadIdx.x;
    const bool f32 = detect_f32(nf, t);

    if (blockIdx.x >= 128) {
        // ---- coords part ----
        int idx = (blockIdx.x - 128) * 256 + t;
        if (idx < 4 * 256 * 4 * 3) {
            int x = idx % 3;
            int a = (idx / 3) & 3;
            int node = idx / 12;
            float v = ldf(coords, idx, f32) + cupd[node * 3 + x] * ldf(mask, node * 4 + a, f32);
            if (f32) ((float*)d_out)[idx] = v;
            else     ((u16*)d_out)[idx] = f2bu(v);
        }
        return;
    }

    // ---- node MLP + LN ----
    const int row0 = blockIdx.x * 8;
    __shared__ float x_l[8][384];
    __shared__ float hs[8][256];
    __shared__ float ho[8][128];
    for (int idx = t; idx < 8 * 384; idx += 256) {
        int r = idx / 384, k = idx % 384;
        x_l[r][k] = (k < 128) ? ldf(nf, (row0 + r) * 128 + k, f32)
                              : agg[(row0 + r) * 256 + (k - 128)];
    }
    __syncthreads();
    {
        float a1[8] = {0.f, 0.f, 0.f, 0.f, 0.f, 0.f, 0.f, 0.f};
        for (int k = 0; k < 384; k++) {
            float wv = ldf(Wn1, k * 256 + t, f32);
#pragma unroll
            for (int r = 0; r < 8; r++) a1[r] += x_l[r][k] * wv;
        }
        float b1 = ldf(bn1, t, f32);
#pragma unroll
        for (int r = 0; r < 8; r++) hs[r][t] = siluf(a1[r] + b1);
    }
    __syncthreads();
    {
        int cc = t & 127, rg = (t >> 7) * 4;
        float a2[4] = {0.f, 0.f, 0.f, 0.f};
        for (int k = 0; k < 256; k++) {
            float wv = ldf(Wn2, k * 128 + cc, f32);
#pragma unroll
            for (int r = 0; r < 4; r++) a2[r] += hs[rg + r][k] * wv;
        }
        float b2 = ldf(bn2, cc, f32);
#pragma unroll
        for (int r = 0; r < 4; r++) ho[rg + r][cc] = a2[r] + b2;
    }
    __syncthreads();
    {
        int row = t >> 5, s = t & 31;
        float sm = 0.f, sq = 0.f;
#pragma unroll
        for (int u = 0; u < 4; u++) {
            float v = ho[row][s + 32 * u];
            sm += v; sq += v * v;
        }
#pragma unroll
        for (int d = 1; d < 32; d <<= 1) {
            sm += __shfl_xor(sm, d);
            sq += __shfl_xor(sq, d);
        }
        float mu = sm * (1.f / 128.f);
        float var = sq * (1.f / 128.f) - mu * mu;
        float inv = rsqrtf(var + 1e-5f);
#pragma unroll
        for (int u = 0; u < 4; u++) {
            int cc = s + 32 * u;
            float y = (ho[row][cc] - mu) * inv;
            float outv = y * ldf(gamma, cc, f32) + ldf(beta, cc, f32);
            int oi = 12288 + (row0 + row) * 128 + cc;
            if (f32) ((float*)d_out)[oi] = outv;
            else     ((u16*)d_out)[oi] = f2bu(outv);
        }
    }
}

extern "C" void kernel_launch(void* const* d_in, const int* in_sizes, int n_in,
                              void* d_out, int out_size, void* d_ws, size_t ws_size,
                              hipStream_t stream)
{
    const void* coords = d_in[0];
    const void* nf     = d_in[1];
    const void* mask   = d_in[2];
    const int* resid   = (const int*)d_in[3];
    const void* We1 = d_in[4];
    const void* be1 = d_in[5];
    const void* We2 = d_in[6];
    const void* be2 = d_in[7];
    const void* Wn1 = d_in[8];
    const void* bn1 = d_in[9];
    const void* Wn2 = d_in[10];
    const void* bn2 = d_in[11];
    const void* gamma = d_in[12];
    const void* beta  = d_in[13];
    const void* Wc1 = d_in[14];
    const void* bc1 = d_in[15];
    const void* Wc2 = d_in[16];
    const void* bc2 = d_in[17];

    // workspace layout: [pad][f32 arrays][f16 weight arrays] ~3.96 MB
    float* f   = (float*)d_ws + 16;
    float* cbar = f;                 // 1024*3
    float* pi2  = cbar + 3072;       // 1024*256
    float* qd   = pi2 + 262144;      // 1024*256
    float* Ttab = qd + 262144;       // 511*256
    float* agg  = Ttab + 130816;     // 1024*256
    float* cupd = agg + 262144;      // 1024*3
    u16* We2X = (u16*)(cupd + 3072); // 256*256 f16, fragment-major X layout
    u16* Wc1X = We2X + 65536;        // 256*256 f16

    hipLaunchKernelGGL(prep_kernel, dim3(895), dim3(256), 0, stream,
                       coords, nf, We1, be1, We2, Wc1, cbar, pi2, qd, Ttab, We2X, Wc1X);
    hipLaunchKernelGGL(edge_kernel, dim3(1024), dim3(512), 0, stream,
                       resid, pi2, qd, Ttab, cbar, We2X, Wc1X, be2, bc1, Wc2, bc2, nf, agg, cupd);
    hipLaunchKernelGGL(out_kernel, dim3(176), dim3(256), 0, stream,
                       nf, agg, Wn1, bn1, Wn2, bn2, gamma, beta, coords, mask, cupd, d_out);
}